// Round 6
// baseline (1035.160 us; speedup 1.0000x reference)
//
#include <hip/hip_runtime.h>
#include <hip/hip_fp16.h>

// CorrectAndSmooth on MI355X.
// N=100000 nodes, C=48 classes, E=1.6M edges, 10+10 propagation layers.
// R5: gather restructured for MLP: 6 lanes/node (16B/lane), unroll-8 edge
//     loop (8 outstanding 16B gathers/lane), CSR stores byte offsets.

constexpr int NN  = 100000;
constexpr int NC  = 48;
constexpr int NE  = 1600000;
constexpr int NTR = 10000;
constexpr int NVA = 10000;
constexpr float ALPHA1 = 0.979f;   // correction
constexpr float ALPHA2 = 0.756f;   // smoothing
constexpr int ROWB = NC * 2;       // 96 bytes per fp16 row

constexpr int NS = 3;                         // src slices (kept from R4)
constexpr int SW = (NN + NS - 1) / NS;
constexpr int N3 = NN * NS;
constexpr int SCAN_B = 1024;
constexpr int NB3 = (N3 + SCAN_B - 1) / SCAN_B;

union H4 { uint2 u; __half2 h[2]; };

__device__ __forceinline__ float4 h4f(uint2 q) {
    H4 t; t.u = q;
    float2 a = __half22float2(t.h[0]), b = __half22float2(t.h[1]);
    return make_float4(a.x, a.y, b.x, b.y);
}
__device__ __forceinline__ uint2 f4h(float4 v) {
    H4 t;
    t.h[0] = __float22half2_rn(make_float2(v.x, v.y));
    t.h[1] = __float22half2_rn(make_float2(v.z, v.w));
    return t.u;
}

union H8 { uint4 u; __half2 h[4]; };

// accumulate 8 halfs from q into A (ch0-3) and B (ch4-7)
__device__ __forceinline__ void h8acc(uint4 q, float4& A, float4& B) {
    H8 t; t.u = q;
    float2 f0 = __half22float2(t.h[0]), f1 = __half22float2(t.h[1]);
    float2 f2 = __half22float2(t.h[2]), f3 = __half22float2(t.h[3]);
    A.x += f0.x; A.y += f0.y; A.z += f1.x; A.w += f1.y;
    B.x += f2.x; B.y += f2.y; B.z += f3.x; B.w += f3.y;
}

// ---------- preprocessing ----------

__global__ void k_count3(const int* __restrict__ src, const int* __restrict__ dst,
                         int* __restrict__ deg3) {
    int e = blockIdx.x * blockDim.x + threadIdx.x;
    if (e < NE) {
        int d = dst[e], s = src[e] / SW;
        atomicAdd(&deg3[d * NS + s], 1);
    }
}

__global__ void k_bsum(const int* __restrict__ deg3, int* __restrict__ bsum) {
    int base = blockIdx.x * SCAN_B + threadIdx.x * 4;
    int s = 0;
    if (base + 3 < N3) {
        int4 q = *reinterpret_cast<const int4*>(deg3 + base);
        s = q.x + q.y + q.z + q.w;
    } else {
#pragma unroll
        for (int i = 0; i < 4; ++i) if (base + i < N3) s += deg3[base + i];
    }
    for (int o = 32; o > 0; o >>= 1) s += __shfl_down(s, o, 64);
    __shared__ int sh[4];
    if ((threadIdx.x & 63) == 0) sh[threadIdx.x >> 6] = s;
    __syncthreads();
    if (threadIdx.x == 0) bsum[blockIdx.x] = sh[0] + sh[1] + sh[2] + sh[3];
}

__global__ void k_bscan(int* __restrict__ bsum) {
    __shared__ int sh[512];
    int t = threadIdx.x;
    int v = (t < NB3) ? bsum[t] : 0;
    sh[t] = v;
    __syncthreads();
    for (int o = 1; o < 512; o <<= 1) {
        int u = (t >= o) ? sh[t - o] : 0;
        __syncthreads();
        sh[t] += u;
        __syncthreads();
    }
    if (t < NB3) bsum[t] = sh[t] - v;
}

__global__ void k_scatter(const int* __restrict__ deg3, const int* __restrict__ boff,
                          int* __restrict__ rowp3) {
    int base = blockIdx.x * SCAN_B + threadIdx.x * 4;
    int v0 = 0, v1 = 0, v2 = 0, v3 = 0;
    if (base + 3 < N3) {
        int4 q = *reinterpret_cast<const int4*>(deg3 + base);
        v0 = q.x; v1 = q.y; v2 = q.z; v3 = q.w;
    } else {
        if (base     < N3) v0 = deg3[base];
        if (base + 1 < N3) v1 = deg3[base + 1];
        if (base + 2 < N3) v2 = deg3[base + 2];
        if (base + 3 < N3) v3 = deg3[base + 3];
    }
    int tsum = v0 + v1 + v2 + v3;
    int lane = threadIdx.x & 63, w = threadIdx.x >> 6;
    int inc = tsum;
    for (int o = 1; o < 64; o <<= 1) {
        int u = __shfl_up(inc, o, 64);
        if (lane >= o) inc += u;
    }
    __shared__ int wsum[4];
    if (lane == 63) wsum[w] = inc;
    __syncthreads();
    int woff = 0;
#pragma unroll
    for (int i = 0; i < 4; ++i) if (i < w) woff += wsum[i];
    int ex = boff[blockIdx.x] + woff + inc - tsum;
    if (base     < N3) rowp3[base]     = ex;
    if (base + 1 < N3) rowp3[base + 1] = ex + v0;
    if (base + 2 < N3) rowp3[base + 2] = ex + v0 + v1;
    if (base + 3 < N3) rowp3[base + 3] = ex + v0 + v1 + v2;
    if (blockIdx.x == 0 && threadIdx.x == 0) rowp3[N3] = NE;
}

__global__ void k_norm(const int* __restrict__ rowp3, float* __restrict__ norm) {
    int v = blockIdx.x * blockDim.x + threadIdx.x;
    if (v < NN) {
        int d = rowp3[(v + 1) * NS] - rowp3[v * NS];
        if (d < 1) d = 1;
        norm[v] = rsqrtf((float)d);
    }
}

// csr stores BYTE offset of src row (src*96)
__global__ void k_fill3(const int* __restrict__ src, const int* __restrict__ dst,
                        const int* __restrict__ rowp3, int* __restrict__ fill3,
                        int* __restrict__ csr) {
    int e = blockIdx.x * blockDim.x + threadIdx.x;
    if (e < NE) {
        int sv = src[e];
        int cell = dst[e] * NS + sv / SW;
        int p = atomicAdd(&fill3[cell], 1);
        csr[rowp3[cell] + p] = sv * ROWB;
    }
}

// ---------- error build + sigma ----------
__global__ void k_error(const float* __restrict__ y_soft, const int* __restrict__ y_true,
                        const int* __restrict__ train, const float* __restrict__ norm,
                        __half* __restrict__ A, __half* __restrict__ last,
                        float* __restrict__ sig) {
    int t = blockIdx.x * blockDim.x + threadIdx.x;
    float a = 0.f;
    if (t < NTR * NC) {
        int j = t / NC, c = t % NC;
        float e = ((c == y_true[j]) ? 1.0f : 0.0f) - y_soft[(size_t)j * NC + c];
        int r = train[j];
        A[(size_t)r * NC + c]    = __float2half(norm[r] * e);
        last[(size_t)r * NC + c] = __float2half((1.0f - ALPHA1) * e);
        a = fabsf(e);
    }
    for (int off = 32; off > 0; off >>= 1) a += __shfl_down(a, off, 64);
    if ((threadIdx.x & 63) == 0) atomicAdd(sig, a);
}

// ---------- propagation layer ----------
// 6 lanes/node, 16B (8 ch) per lane. yin holds u = norm .* y (pre-scaled).
//   y_d = clip(last_d + alpha*norm_d * sum u_src, lo, hi); yout = PRE? norm*y : y
template <bool PRE>
__global__ __launch_bounds__(256)
void k_gather(const __half* __restrict__ yin, __half* __restrict__ yout,
              const __half* __restrict__ last, const float* __restrict__ norm,
              const int* __restrict__ rowp3, const int* __restrict__ csrB,
              float alpha, float lo, float hi) {
    int t = blockIdx.x * blockDim.x + threadIdx.x;
    if (t >= NN * 6) return;
    int node = t / 6, chb = (t % 6) * 16;   // byte offset of this lane's 16B
    const char* yb = reinterpret_cast<const char*>(yin) + chb;
    int beg = rowp3[node * NS], end = rowp3[node * NS + NS];
    float4 A0 = make_float4(0, 0, 0, 0), B0 = make_float4(0, 0, 0, 0);
    float4 A1 = make_float4(0, 0, 0, 0), B1 = make_float4(0, 0, 0, 0);
    int k = beg;
    for (; k + 8 <= end; k += 8) {
        int o0 = csrB[k],     o1 = csrB[k + 1], o2 = csrB[k + 2], o3 = csrB[k + 3];
        int o4 = csrB[k + 4], o5 = csrB[k + 5], o6 = csrB[k + 6], o7 = csrB[k + 7];
        uint4 q0 = *reinterpret_cast<const uint4*>(yb + o0);
        uint4 q1 = *reinterpret_cast<const uint4*>(yb + o1);
        uint4 q2 = *reinterpret_cast<const uint4*>(yb + o2);
        uint4 q3 = *reinterpret_cast<const uint4*>(yb + o3);
        uint4 q4 = *reinterpret_cast<const uint4*>(yb + o4);
        uint4 q5 = *reinterpret_cast<const uint4*>(yb + o5);
        uint4 q6 = *reinterpret_cast<const uint4*>(yb + o6);
        uint4 q7 = *reinterpret_cast<const uint4*>(yb + o7);
        h8acc(q0, A0, B0); h8acc(q1, A1, B1);
        h8acc(q2, A0, B0); h8acc(q3, A1, B1);
        h8acc(q4, A0, B0); h8acc(q5, A1, B1);
        h8acc(q6, A0, B0); h8acc(q7, A1, B1);
    }
    for (; k < end; ++k) {
        uint4 q = *reinterpret_cast<const uint4*>(yb + csrB[k]);
        h8acc(q, A0, B0);
    }
    A0.x += A1.x; A0.y += A1.y; A0.z += A1.z; A0.w += A1.w;
    B0.x += B1.x; B0.y += B1.y; B0.z += B1.z; B0.w += B1.w;

    float nd = alpha * norm[node];
    const char* lb = reinterpret_cast<const char*>(last) + (size_t)node * ROWB + chb;
    H8 lt; lt.u = *reinterpret_cast<const uint4*>(lb);
    float2 l0 = __half22float2(lt.h[0]), l1 = __half22float2(lt.h[1]);
    float2 l2 = __half22float2(lt.h[2]), l3 = __half22float2(lt.h[3]);
    float o0 = fminf(fmaxf(fmaf(nd, A0.x, l0.x), lo), hi);
    float o1 = fminf(fmaxf(fmaf(nd, A0.y, l0.y), lo), hi);
    float o2 = fminf(fmaxf(fmaf(nd, A0.z, l1.x), lo), hi);
    float o3 = fminf(fmaxf(fmaf(nd, A0.w, l1.y), lo), hi);
    float o4 = fminf(fmaxf(fmaf(nd, B0.x, l2.x), lo), hi);
    float o5 = fminf(fmaxf(fmaf(nd, B0.y, l2.y), lo), hi);
    float o6 = fminf(fmaxf(fmaf(nd, B0.z, l3.x), lo), hi);
    float o7 = fminf(fmaxf(fmaf(nd, B0.w, l3.y), lo), hi);
    if (PRE) {
        float w = norm[node];
        o0 *= w; o1 *= w; o2 *= w; o3 *= w; o4 *= w; o5 *= w; o6 *= w; o7 *= w;
    }
    H8 ot;
    ot.h[0] = __float22half2_rn(make_float2(o0, o1));
    ot.h[1] = __float22half2_rn(make_float2(o2, o3));
    ot.h[2] = __float22half2_rn(make_float2(o4, o5));
    ot.h[3] = __float22half2_rn(make_float2(o6, o7));
    char* ob = reinterpret_cast<char*>(yout) + (size_t)node * ROWB + chb;
    *reinterpret_cast<uint4*>(ob) = ot.u;
}

// ---------- scale prep ----------
__global__ void k_rowabs(const __half* __restrict__ se, float* __restrict__ rowabs) {
    int v = blockIdx.x * blockDim.x + threadIdx.x;
    if (v >= NN) return;
    const uint2* p = reinterpret_cast<const uint2*>(se + (size_t)v * NC);
    float s = 0.f;
#pragma unroll
    for (int k = 0; k < 12; ++k) {
        float4 x = h4f(p[k]);
        s += fabsf(x.x) + fabsf(x.y) + fabsf(x.z) + fabsf(x.w);
    }
    rowabs[v] = s;
}

__device__ __forceinline__ int cat_at(int i, const int* __restrict__ tr,
                                      const int* __restrict__ va, const int* __restrict__ te) {
    if (i < NTR)        return tr[i];
    if (i < NTR + NVA)  return va[i - NTR];
    return te[i - NTR - NVA];
}

// In-place on A (unscaled smoothed_error in, pre-scaled y_all out).
__global__ void k_phaseD(__half* __restrict__ se_yall, const float* __restrict__ y_soft,
                         const float* __restrict__ rowabs, const float* __restrict__ sig,
                         const int* __restrict__ y_true,
                         const int* __restrict__ tr, const int* __restrict__ va,
                         const int* __restrict__ te, const float* __restrict__ norm,
                         __half* __restrict__ last) {
    int t = blockIdx.x * blockDim.x + threadIdx.x;
    if (t >= NN * 12) return;
    int i = t / 12, ch = (t % 12) * 4;
    int cid = cat_at(i, tr, va, te);
    float4 o;
    if (i < NTR) {
        int yt = y_true[i];
        o.x = (ch + 0 == yt) ? 1.f : 0.f;
        o.y = (ch + 1 == yt) ? 1.f : 0.f;
        o.z = (ch + 2 == yt) ? 1.f : 0.f;
        o.w = (ch + 3 == yt) ? 1.f : 0.f;
    } else {
        // scale >= 0 or +inf or NaN; (isinf || >1000) == (>1000), NaN caught below.
        float s = (sig[0] * (1.0f / NTR)) / rowabs[i];
        if (s > 1000.0f) s = 1.0f;
        float4 e  = h4f(*reinterpret_cast<const uint2*>(se_yall + (size_t)cid * NC + ch));
        float4 ys = *reinterpret_cast<const float4*>(y_soft + (size_t)i * NC + ch);
        o.x = ys.x + s * e.x; if (o.x != o.x) o.x = ys.x;
        o.y = ys.y + s * e.y; if (o.y != o.y) o.y = ys.y;
        o.z = ys.z + s * e.z; if (o.z != o.z) o.z = ys.z;
        o.w = ys.w + s * e.w; if (o.w != o.w) o.w = ys.w;
    }
    float w = norm[cid];
    *reinterpret_cast<uint2*>(se_yall + (size_t)cid * NC + ch) =
        f4h(make_float4(o.x * w, o.y * w, o.z * w, o.w * w));
    float la = 1.0f - ALPHA2;
    *reinterpret_cast<uint2*>(last + (size_t)cid * NC + ch) =
        f4h(make_float4(la * o.x, la * o.y, la * o.z, la * o.w));
}

// out[i] = yin[cat[i]]  (fp16 -> f32)
__global__ void k_outgather(const __half* __restrict__ yin, float* __restrict__ out,
                            const int* __restrict__ tr, const int* __restrict__ va,
                            const int* __restrict__ te) {
    int t = blockIdx.x * blockDim.x + threadIdx.x;
    if (t >= NN * 12) return;
    int i = t / 12, ch = (t % 12) * 4;
    int cid = cat_at(i, tr, va, te);
    float4 v = h4f(*reinterpret_cast<const uint2*>(yin + (size_t)cid * NC + ch));
    *reinterpret_cast<float4*>(out + (size_t)i * NC + ch) = v;
}

extern "C" void kernel_launch(void* const* d_in, const int* in_sizes, int n_in,
                              void* d_out, int out_size, void* d_ws, size_t ws_size,
                              hipStream_t stream) {
    const float* y_soft = (const float*)d_in[0];
    const int*   y_true = (const int*)d_in[1];
    const int*   src    = (const int*)d_in[2];
    const int*   dst    = (const int*)d_in[3];
    const int*   tr     = (const int*)d_in[4];
    const int*   va     = (const int*)d_in[5];
    const int*   te     = (const int*)d_in[6];
    float* out = (float*)d_out;

    char* ws = (char*)d_ws;
    size_t off = 0;
    auto alloc = [&](size_t bytes) -> void* {
        void* p = ws + off;
        off += (bytes + 255) & ~(size_t)255;
        return p;
    };
    __half* A      = (__half*)alloc((size_t)NN * NC * 2);   // 9.6 MB
    __half* B      = (__half*)alloc((size_t)NN * NC * 2);   // 9.6 MB
    __half* last   = (__half*)alloc((size_t)NN * NC * 2);   // 9.6 MB
    int*    csr    = (int*)   alloc((size_t)NE * 4);        // 6.4 MB
    int*    deg3   = (int*)   alloc((size_t)N3 * 4);
    int*    fill3  = (int*)   alloc((size_t)N3 * 4);
    int*    rowp3  = (int*)   alloc((size_t)(N3 + 1) * 4);
    float*  norm   = (float*) alloc((size_t)NN * 4);
    float*  rowabs = (float*) alloc((size_t)NN * 4);
    int*    bsum   = (int*)   alloc((size_t)NB3 * 4);
    float*  sig    = (float*) alloc(256);

    (void)hipMemsetAsync(deg3,  0, (size_t)N3 * 4, stream);
    (void)hipMemsetAsync(fill3, 0, (size_t)N3 * 4, stream);
    (void)hipMemsetAsync(A,     0, (size_t)NN * NC * 2, stream);
    (void)hipMemsetAsync(last,  0, (size_t)NN * NC * 2, stream);
    (void)hipMemsetAsync(sig,   0, 4, stream);

    k_count3 <<<NE / 256, 256, 0, stream>>>(src, dst, deg3);
    k_bsum   <<<NB3, 256, 0, stream>>>(deg3, bsum);
    k_bscan  <<<1, 512, 0, stream>>>(bsum);
    k_scatter<<<NB3, 256, 0, stream>>>(deg3, bsum, rowp3);
    k_norm   <<<(NN + 255) / 256, 256, 0, stream>>>(rowp3, norm);
    k_fill3  <<<NE / 256, 256, 0, stream>>>(src, dst, rowp3, fill3, csr);
    k_error  <<<(NTR * NC) / 256, 256, 0, stream>>>(y_soft, y_true, tr, norm, A, last, sig);

    const int G6  = (NN * 6 + 255) / 256;
    const int G12 = (NN * 12 + 255) / 256;

    // propagation 1: A -> ... -> A (10 layers); last layer unscaled
    __half* cur = A; __half* oth = B;
    for (int l = 0; l < 10; ++l) {
        if (l < 9)
            k_gather<true><<<G6, 256, 0, stream>>>(cur, oth, last, norm, rowp3, csr,
                                                   ALPHA1, -1.f, 1.f);
        else
            k_gather<false><<<G6, 256, 0, stream>>>(cur, oth, last, norm, rowp3, csr,
                                                    ALPHA1, -1.f, 1.f);
        __half* t2 = cur; cur = oth; oth = t2;
    }

    k_rowabs<<<(NN + 255) / 256, 256, 0, stream>>>(A, rowabs);
    // in-place: A := norm .* y_all; last := (1-ALPHA2)*y_all
    k_phaseD<<<G12, 256, 0, stream>>>(A, y_soft, rowabs, sig, y_true,
                                      tr, va, te, norm, last);

    // propagation 2: A -> ... -> A (10 layers); last layer unscaled
    cur = A; oth = B;
    for (int l = 0; l < 10; ++l) {
        if (l < 9)
            k_gather<true><<<G6, 256, 0, stream>>>(cur, oth, last, norm, rowp3, csr,
                                                   ALPHA2, 0.f, 1.f);
        else
            k_gather<false><<<G6, 256, 0, stream>>>(cur, oth, last, norm, rowp3, csr,
                                                    ALPHA2, 0.f, 1.f);
        __half* t2 = cur; cur = oth; oth = t2;
    }

    // d_out[i] = A[cat[i]]
    k_outgather<<<G12, 256, 0, stream>>>(A, out, tr, va, te);
}

// Round 7
// 857.756 us; speedup vs baseline: 1.2068x; 1.2068x over previous
//
#include <hip/hip_runtime.h>
#include <hip/hip_fp16.h>

// CorrectAndSmooth on MI355X.
// N=100000 nodes, C=48 classes, E=1.6M edges, 10+10 propagation layers.
// R6: (1) k_error two-stage reduce (kills 7500 same-address atomics, was 99us);
//     (2) feature rows padded 96B->128B aligned: every edge-gather touches
//         exactly one 128B L2 line (was avg 1.5).

constexpr int NN  = 100000;
constexpr int NC  = 48;
constexpr int NE  = 1600000;
constexpr int NTR = 10000;
constexpr int NVA = 10000;
constexpr float ALPHA1 = 0.979f;   // correction
constexpr float ALPHA2 = 0.756f;   // smoothing
constexpr int ROWH = 64;           // halfs per padded row (128B)
constexpr int ROWB = 128;          // bytes per padded row

constexpr int NS = 3;                         // src slices (kept from R4)
constexpr int SW = (NN + NS - 1) / NS;
constexpr int N3 = NN * NS;
constexpr int SCAN_B = 1024;
constexpr int NB3 = (N3 + SCAN_B - 1) / SCAN_B;
constexpr int NEB = (NTR * 12 + 255) / 256;   // k_error blocks (469)

union H4 { uint2 u; __half2 h[2]; };

__device__ __forceinline__ float4 h4f(uint2 q) {
    H4 t; t.u = q;
    float2 a = __half22float2(t.h[0]), b = __half22float2(t.h[1]);
    return make_float4(a.x, a.y, b.x, b.y);
}
__device__ __forceinline__ uint2 f4h(float4 v) {
    H4 t;
    t.h[0] = __float22half2_rn(make_float2(v.x, v.y));
    t.h[1] = __float22half2_rn(make_float2(v.z, v.w));
    return t.u;
}

union H8 { uint4 u; __half2 h[4]; };

__device__ __forceinline__ void h8acc(uint4 q, float4& A, float4& B) {
    H8 t; t.u = q;
    float2 f0 = __half22float2(t.h[0]), f1 = __half22float2(t.h[1]);
    float2 f2 = __half22float2(t.h[2]), f3 = __half22float2(t.h[3]);
    A.x += f0.x; A.y += f0.y; A.z += f1.x; A.w += f1.y;
    B.x += f2.x; B.y += f2.y; B.z += f3.x; B.w += f3.y;
}

// ---------- preprocessing ----------

__global__ void k_count3(const int* __restrict__ src, const int* __restrict__ dst,
                         int* __restrict__ deg3) {
    int e = blockIdx.x * blockDim.x + threadIdx.x;
    if (e < NE) {
        int d = dst[e], s = src[e] / SW;
        atomicAdd(&deg3[d * NS + s], 1);
    }
}

__global__ void k_bsum(const int* __restrict__ deg3, int* __restrict__ bsum) {
    int base = blockIdx.x * SCAN_B + threadIdx.x * 4;
    int s = 0;
    if (base + 3 < N3) {
        int4 q = *reinterpret_cast<const int4*>(deg3 + base);
        s = q.x + q.y + q.z + q.w;
    } else {
#pragma unroll
        for (int i = 0; i < 4; ++i) if (base + i < N3) s += deg3[base + i];
    }
    for (int o = 32; o > 0; o >>= 1) s += __shfl_down(s, o, 64);
    __shared__ int sh[4];
    if ((threadIdx.x & 63) == 0) sh[threadIdx.x >> 6] = s;
    __syncthreads();
    if (threadIdx.x == 0) bsum[blockIdx.x] = sh[0] + sh[1] + sh[2] + sh[3];
}

__global__ void k_bscan(int* __restrict__ bsum) {
    __shared__ int sh[512];
    int t = threadIdx.x;
    int v = (t < NB3) ? bsum[t] : 0;
    sh[t] = v;
    __syncthreads();
    for (int o = 1; o < 512; o <<= 1) {
        int u = (t >= o) ? sh[t - o] : 0;
        __syncthreads();
        sh[t] += u;
        __syncthreads();
    }
    if (t < NB3) bsum[t] = sh[t] - v;
}

__global__ void k_scatter(const int* __restrict__ deg3, const int* __restrict__ boff,
                          int* __restrict__ rowp3) {
    int base = blockIdx.x * SCAN_B + threadIdx.x * 4;
    int v0 = 0, v1 = 0, v2 = 0, v3 = 0;
    if (base + 3 < N3) {
        int4 q = *reinterpret_cast<const int4*>(deg3 + base);
        v0 = q.x; v1 = q.y; v2 = q.z; v3 = q.w;
    } else {
        if (base     < N3) v0 = deg3[base];
        if (base + 1 < N3) v1 = deg3[base + 1];
        if (base + 2 < N3) v2 = deg3[base + 2];
        if (base + 3 < N3) v3 = deg3[base + 3];
    }
    int tsum = v0 + v1 + v2 + v3;
    int lane = threadIdx.x & 63, w = threadIdx.x >> 6;
    int inc = tsum;
    for (int o = 1; o < 64; o <<= 1) {
        int u = __shfl_up(inc, o, 64);
        if (lane >= o) inc += u;
    }
    __shared__ int wsum[4];
    if (lane == 63) wsum[w] = inc;
    __syncthreads();
    int woff = 0;
#pragma unroll
    for (int i = 0; i < 4; ++i) if (i < w) woff += wsum[i];
    int ex = boff[blockIdx.x] + woff + inc - tsum;
    if (base     < N3) rowp3[base]     = ex;
    if (base + 1 < N3) rowp3[base + 1] = ex + v0;
    if (base + 2 < N3) rowp3[base + 2] = ex + v0 + v1;
    if (base + 3 < N3) rowp3[base + 3] = ex + v0 + v1 + v2;
    if (blockIdx.x == 0 && threadIdx.x == 0) rowp3[N3] = NE;
}

__global__ void k_norm(const int* __restrict__ rowp3, float* __restrict__ norm) {
    int v = blockIdx.x * blockDim.x + threadIdx.x;
    if (v < NN) {
        int d = rowp3[(v + 1) * NS] - rowp3[v * NS];
        if (d < 1) d = 1;
        norm[v] = rsqrtf((float)d);
    }
}

// csr stores BYTE offset of padded src row (src*128)
__global__ void k_fill3(const int* __restrict__ src, const int* __restrict__ dst,
                        const int* __restrict__ rowp3, int* __restrict__ fill3,
                        int* __restrict__ csr) {
    int e = blockIdx.x * blockDim.x + threadIdx.x;
    if (e < NE) {
        int sv = src[e];
        int cell = dst[e] * NS + sv / SW;
        int p = atomicAdd(&fill3[cell], 1);
        csr[rowp3[cell] + p] = sv * ROWB;
    }
}

// ---------- error build + sigma (two-stage, no global atomics) ----------
// thread = (train row j, 4 channels). A[train[j]] = norm*(onehot - y_soft[j]) (fp16),
// last[train[j]] = (1-ALPHA1)*(...)  ; partial[block] = block-sum |error|
__global__ void k_error(const float* __restrict__ y_soft, const int* __restrict__ y_true,
                        const int* __restrict__ train, const float* __restrict__ norm,
                        __half* __restrict__ A, __half* __restrict__ last,
                        float* __restrict__ partial) {
    int t = blockIdx.x * blockDim.x + threadIdx.x;
    float a = 0.f;
    if (t < NTR * 12) {
        int j = t / 12, ch = (t % 12) * 4;
        int yt = y_true[j];
        float4 ys = *reinterpret_cast<const float4*>(y_soft + (size_t)j * NC + ch);
        float e0 = ((ch + 0 == yt) ? 1.f : 0.f) - ys.x;
        float e1 = ((ch + 1 == yt) ? 1.f : 0.f) - ys.y;
        float e2 = ((ch + 2 == yt) ? 1.f : 0.f) - ys.z;
        float e3 = ((ch + 3 == yt) ? 1.f : 0.f) - ys.w;
        int r = train[j];
        float w = norm[r];
        *reinterpret_cast<uint2*>(A + (size_t)r * ROWH + ch) =
            f4h(make_float4(w * e0, w * e1, w * e2, w * e3));
        float la = 1.0f - ALPHA1;
        *reinterpret_cast<uint2*>(last + (size_t)r * ROWH + ch) =
            f4h(make_float4(la * e0, la * e1, la * e2, la * e3));
        a = fabsf(e0) + fabsf(e1) + fabsf(e2) + fabsf(e3);
    }
    for (int o = 32; o > 0; o >>= 1) a += __shfl_down(a, o, 64);
    __shared__ float sh[4];
    if ((threadIdx.x & 63) == 0) sh[threadIdx.x >> 6] = a;
    __syncthreads();
    if (threadIdx.x == 0) partial[blockIdx.x] = sh[0] + sh[1] + sh[2] + sh[3];
}

__global__ void k_sigsum(const float* __restrict__ partial, float* __restrict__ sig) {
    float a = 0.f;
    for (int i = threadIdx.x; i < NEB; i += 512) a += partial[i];
    for (int o = 32; o > 0; o >>= 1) a += __shfl_down(a, o, 64);
    __shared__ float sh[8];
    if ((threadIdx.x & 63) == 0) sh[threadIdx.x >> 6] = a;
    __syncthreads();
    if (threadIdx.x == 0) {
        float s = 0.f;
#pragma unroll
        for (int i = 0; i < 8; ++i) s += sh[i];
        sig[0] = s;
    }
}

// ---------- propagation layer ----------
// 6 lanes/node, 16B/lane over bytes 0..95 of the 128B-aligned row.
template <bool PRE>
__global__ __launch_bounds__(256)
void k_gather(const __half* __restrict__ yin, __half* __restrict__ yout,
              const __half* __restrict__ last, const float* __restrict__ norm,
              const int* __restrict__ rowp3, const int* __restrict__ csrB,
              float alpha, float lo, float hi) {
    int t = blockIdx.x * blockDim.x + threadIdx.x;
    if (t >= NN * 6) return;
    int node = t / 6, chb = (t % 6) * 16;
    const char* yb = reinterpret_cast<const char*>(yin) + chb;
    int beg = rowp3[node * NS], end = rowp3[node * NS + NS];
    float4 A0 = make_float4(0, 0, 0, 0), B0 = make_float4(0, 0, 0, 0);
    float4 A1 = make_float4(0, 0, 0, 0), B1 = make_float4(0, 0, 0, 0);
    int k = beg;
    for (; k + 8 <= end; k += 8) {
        int o0 = csrB[k],     o1 = csrB[k + 1], o2 = csrB[k + 2], o3 = csrB[k + 3];
        int o4 = csrB[k + 4], o5 = csrB[k + 5], o6 = csrB[k + 6], o7 = csrB[k + 7];
        uint4 q0 = *reinterpret_cast<const uint4*>(yb + o0);
        uint4 q1 = *reinterpret_cast<const uint4*>(yb + o1);
        uint4 q2 = *reinterpret_cast<const uint4*>(yb + o2);
        uint4 q3 = *reinterpret_cast<const uint4*>(yb + o3);
        uint4 q4 = *reinterpret_cast<const uint4*>(yb + o4);
        uint4 q5 = *reinterpret_cast<const uint4*>(yb + o5);
        uint4 q6 = *reinterpret_cast<const uint4*>(yb + o6);
        uint4 q7 = *reinterpret_cast<const uint4*>(yb + o7);
        h8acc(q0, A0, B0); h8acc(q1, A1, B1);
        h8acc(q2, A0, B0); h8acc(q3, A1, B1);
        h8acc(q4, A0, B0); h8acc(q5, A1, B1);
        h8acc(q6, A0, B0); h8acc(q7, A1, B1);
    }
    for (; k < end; ++k) {
        uint4 q = *reinterpret_cast<const uint4*>(yb + csrB[k]);
        h8acc(q, A0, B0);
    }
    A0.x += A1.x; A0.y += A1.y; A0.z += A1.z; A0.w += A1.w;
    B0.x += B1.x; B0.y += B1.y; B0.z += B1.z; B0.w += B1.w;

    float nd = alpha * norm[node];
    const char* lb = reinterpret_cast<const char*>(last) + (size_t)node * ROWB + chb;
    H8 lt; lt.u = *reinterpret_cast<const uint4*>(lb);
    float2 l0 = __half22float2(lt.h[0]), l1 = __half22float2(lt.h[1]);
    float2 l2 = __half22float2(lt.h[2]), l3 = __half22float2(lt.h[3]);
    float o0 = fminf(fmaxf(fmaf(nd, A0.x, l0.x), lo), hi);
    float o1 = fminf(fmaxf(fmaf(nd, A0.y, l0.y), lo), hi);
    float o2 = fminf(fmaxf(fmaf(nd, A0.z, l1.x), lo), hi);
    float o3 = fminf(fmaxf(fmaf(nd, A0.w, l1.y), lo), hi);
    float o4 = fminf(fmaxf(fmaf(nd, B0.x, l2.x), lo), hi);
    float o5 = fminf(fmaxf(fmaf(nd, B0.y, l2.y), lo), hi);
    float o6 = fminf(fmaxf(fmaf(nd, B0.z, l3.x), lo), hi);
    float o7 = fminf(fmaxf(fmaf(nd, B0.w, l3.y), lo), hi);
    if (PRE) {
        float w = norm[node];
        o0 *= w; o1 *= w; o2 *= w; o3 *= w; o4 *= w; o5 *= w; o6 *= w; o7 *= w;
    }
    H8 ot;
    ot.h[0] = __float22half2_rn(make_float2(o0, o1));
    ot.h[1] = __float22half2_rn(make_float2(o2, o3));
    ot.h[2] = __float22half2_rn(make_float2(o4, o5));
    ot.h[3] = __float22half2_rn(make_float2(o6, o7));
    char* ob = reinterpret_cast<char*>(yout) + (size_t)node * ROWB + chb;
    *reinterpret_cast<uint4*>(ob) = ot.u;
}

// ---------- scale prep ----------
__global__ void k_rowabs(const __half* __restrict__ se, float* __restrict__ rowabs) {
    int v = blockIdx.x * blockDim.x + threadIdx.x;
    if (v >= NN) return;
    const uint4* p = reinterpret_cast<const uint4*>(se + (size_t)v * ROWH);
    float s = 0.f;
#pragma unroll
    for (int k = 0; k < 6; ++k) {
        H8 t; t.u = p[k];
        float2 f0 = __half22float2(t.h[0]), f1 = __half22float2(t.h[1]);
        float2 f2 = __half22float2(t.h[2]), f3 = __half22float2(t.h[3]);
        s += fabsf(f0.x) + fabsf(f0.y) + fabsf(f1.x) + fabsf(f1.y)
           + fabsf(f2.x) + fabsf(f2.y) + fabsf(f3.x) + fabsf(f3.y);
    }
    rowabs[v] = s;
}

__device__ __forceinline__ int cat_at(int i, const int* __restrict__ tr,
                                      const int* __restrict__ va, const int* __restrict__ te) {
    if (i < NTR)        return tr[i];
    if (i < NTR + NVA)  return va[i - NTR];
    return te[i - NTR - NVA];
}

// In-place on A (unscaled smoothed_error in, pre-scaled y_all out).
__global__ void k_phaseD(__half* __restrict__ se_yall, const float* __restrict__ y_soft,
                         const float* __restrict__ rowabs, const float* __restrict__ sig,
                         const int* __restrict__ y_true,
                         const int* __restrict__ tr, const int* __restrict__ va,
                         const int* __restrict__ te, const float* __restrict__ norm,
                         __half* __restrict__ last) {
    int t = blockIdx.x * blockDim.x + threadIdx.x;
    if (t >= NN * 12) return;
    int i = t / 12, ch = (t % 12) * 4;
    int cid = cat_at(i, tr, va, te);
    float4 o;
    if (i < NTR) {
        int yt = y_true[i];
        o.x = (ch + 0 == yt) ? 1.f : 0.f;
        o.y = (ch + 1 == yt) ? 1.f : 0.f;
        o.z = (ch + 2 == yt) ? 1.f : 0.f;
        o.w = (ch + 3 == yt) ? 1.f : 0.f;
    } else {
        // scale >= 0 or +inf or NaN; (isinf || >1000) == (>1000), NaN caught below.
        float s = (sig[0] * (1.0f / NTR)) / rowabs[i];
        if (s > 1000.0f) s = 1.0f;
        float4 e  = h4f(*reinterpret_cast<const uint2*>(se_yall + (size_t)cid * ROWH + ch));
        float4 ys = *reinterpret_cast<const float4*>(y_soft + (size_t)i * NC + ch);
        o.x = ys.x + s * e.x; if (o.x != o.x) o.x = ys.x;
        o.y = ys.y + s * e.y; if (o.y != o.y) o.y = ys.y;
        o.z = ys.z + s * e.z; if (o.z != o.z) o.z = ys.z;
        o.w = ys.w + s * e.w; if (o.w != o.w) o.w = ys.w;
    }
    float w = norm[cid];
    *reinterpret_cast<uint2*>(se_yall + (size_t)cid * ROWH + ch) =
        f4h(make_float4(o.x * w, o.y * w, o.z * w, o.w * w));
    float la = 1.0f - ALPHA2;
    *reinterpret_cast<uint2*>(last + (size_t)cid * ROWH + ch) =
        f4h(make_float4(la * o.x, la * o.y, la * o.z, la * o.w));
}

// out[i] = yin[cat[i]]  (fp16 padded -> f32 dense)
__global__ void k_outgather(const __half* __restrict__ yin, float* __restrict__ out,
                            const int* __restrict__ tr, const int* __restrict__ va,
                            const int* __restrict__ te) {
    int t = blockIdx.x * blockDim.x + threadIdx.x;
    if (t >= NN * 12) return;
    int i = t / 12, ch = (t % 12) * 4;
    int cid = cat_at(i, tr, va, te);
    float4 v = h4f(*reinterpret_cast<const uint2*>(yin + (size_t)cid * ROWH + ch));
    *reinterpret_cast<float4*>(out + (size_t)i * NC + ch) = v;
}

extern "C" void kernel_launch(void* const* d_in, const int* in_sizes, int n_in,
                              void* d_out, int out_size, void* d_ws, size_t ws_size,
                              hipStream_t stream) {
    const float* y_soft = (const float*)d_in[0];
    const int*   y_true = (const int*)d_in[1];
    const int*   src    = (const int*)d_in[2];
    const int*   dst    = (const int*)d_in[3];
    const int*   tr     = (const int*)d_in[4];
    const int*   va     = (const int*)d_in[5];
    const int*   te     = (const int*)d_in[6];
    float* out = (float*)d_out;

    char* ws = (char*)d_ws;
    size_t off = 0;
    auto alloc = [&](size_t bytes) -> void* {
        void* p = ws + off;
        off += (bytes + 255) & ~(size_t)255;
        return p;
    };
    __half* A      = (__half*)alloc((size_t)NN * ROWH * 2);   // 12.8 MB
    __half* B      = (__half*)alloc((size_t)NN * ROWH * 2);   // 12.8 MB
    __half* last   = (__half*)alloc((size_t)NN * ROWH * 2);   // 12.8 MB
    int*    csr    = (int*)   alloc((size_t)NE * 4);          // 6.4 MB
    int*    deg3   = (int*)   alloc((size_t)N3 * 4);
    int*    fill3  = (int*)   alloc((size_t)N3 * 4);
    int*    rowp3  = (int*)   alloc((size_t)(N3 + 1) * 4);
    float*  norm   = (float*) alloc((size_t)NN * 4);
    float*  rowabs = (float*) alloc((size_t)NN * 4);
    int*    bsum   = (int*)   alloc((size_t)NB3 * 4);
    float*  partial= (float*) alloc((size_t)NEB * 4);
    float*  sig    = (float*) alloc(256);

    (void)hipMemsetAsync(deg3,  0, (size_t)N3 * 4, stream);
    (void)hipMemsetAsync(fill3, 0, (size_t)N3 * 4, stream);
    (void)hipMemsetAsync(A,     0, (size_t)NN * ROWH * 2, stream);
    (void)hipMemsetAsync(last,  0, (size_t)NN * ROWH * 2, stream);

    k_count3 <<<NE / 256, 256, 0, stream>>>(src, dst, deg3);
    k_bsum   <<<NB3, 256, 0, stream>>>(deg3, bsum);
    k_bscan  <<<1, 512, 0, stream>>>(bsum);
    k_scatter<<<NB3, 256, 0, stream>>>(deg3, bsum, rowp3);
    k_norm   <<<(NN + 255) / 256, 256, 0, stream>>>(rowp3, norm);
    k_fill3  <<<NE / 256, 256, 0, stream>>>(src, dst, rowp3, fill3, csr);
    k_error  <<<NEB, 256, 0, stream>>>(y_soft, y_true, tr, norm, A, last, partial);
    k_sigsum <<<1, 512, 0, stream>>>(partial, sig);

    const int G6  = (NN * 6 + 255) / 256;
    const int G12 = (NN * 12 + 255) / 256;

    // propagation 1: A -> ... -> A (10 layers); last layer unscaled
    __half* cur = A; __half* oth = B;
    for (int l = 0; l < 10; ++l) {
        if (l < 9)
            k_gather<true><<<G6, 256, 0, stream>>>(cur, oth, last, norm, rowp3, csr,
                                                   ALPHA1, -1.f, 1.f);
        else
            k_gather<false><<<G6, 256, 0, stream>>>(cur, oth, last, norm, rowp3, csr,
                                                    ALPHA1, -1.f, 1.f);
        __half* t2 = cur; cur = oth; oth = t2;
    }

    k_rowabs<<<(NN + 255) / 256, 256, 0, stream>>>(A, rowabs);
    // in-place: A := norm .* y_all; last := (1-ALPHA2)*y_all
    k_phaseD<<<G12, 256, 0, stream>>>(A, y_soft, rowabs, sig, y_true,
                                      tr, va, te, norm, last);

    // propagation 2: A -> ... -> A (10 layers); last layer unscaled
    cur = A; oth = B;
    for (int l = 0; l < 10; ++l) {
        if (l < 9)
            k_gather<true><<<G6, 256, 0, stream>>>(cur, oth, last, norm, rowp3, csr,
                                                   ALPHA2, 0.f, 1.f);
        else
            k_gather<false><<<G6, 256, 0, stream>>>(cur, oth, last, norm, rowp3, csr,
                                                    ALPHA2, 0.f, 1.f);
        __half* t2 = cur; cur = oth; oth = t2;
    }

    // d_out[i] = A[cat[i]]
    k_outgather<<<G12, 256, 0, stream>>>(A, out, tr, va, te);
}